// Round 1
// baseline (1323.003 us; speedup 1.0000x reference)
//
#include <hip/hip_runtime.h>

typedef unsigned short u16;
typedef unsigned int u32;
typedef __attribute__((ext_vector_type(8))) short short8;
typedef __attribute__((ext_vector_type(4))) float f32x4;

#define SEQ 2048
#define DIM 1024
#define DINNER 2048
#define NPROJ 33
#define NPROJ_PAD 48

__device__ __forceinline__ u16 f2bf(float f) {
  union { float f; u32 u; } v; v.f = f;
  u32 r = (v.u + 0x7fffu + ((v.u >> 16) & 1u)) >> 16;
  return (u16)r;
}
__device__ __forceinline__ float bf2f(u16 s) {
  union { u32 u; float f; } v; v.u = ((u32)s) << 16;
  return v.f;
}
__device__ __forceinline__ void async16(const void* g, void* l) {
  __builtin_amdgcn_global_load_lds(
      (const __attribute__((address_space(1))) u32*)g,
      (__attribute__((address_space(3))) u32*)l, 16, 0, 0);
}

// ---------------- cast kernels ----------------
__global__ void cast_f2b_kernel(const float* __restrict__ src, u16* __restrict__ dst, int n) {
  int i = blockIdx.x * 256 + threadIdx.x;
  if (i < n) dst[i] = f2bf(src[i]);
}

// x_proj_w (33,2048) -> padded bf16 (48,2048), rows 33..47 = 0
__global__ void cast_w2pad_kernel(const float* __restrict__ src, u16* __restrict__ dst) {
  int i = blockIdx.x * 256 + threadIdx.x;  // 48*2048
  int j = i >> 11, k = i & 2047;
  dst[i] = (j < NPROJ) ? f2bf(src[j * 2048 + k]) : (u16)0;
}

// ---------------- layernorm (row=1024) -> bf16 ----------------
__global__ __launch_bounds__(256) void ln_kernel(const float* __restrict__ x,
                                                 const float* __restrict__ w,
                                                 const float* __restrict__ b,
                                                 u16* __restrict__ h) {
  const int row = blockIdx.x;
  const int tid = threadIdx.x;
  const int lane = tid & 63, wave = tid >> 6;
  const float4 v = ((const float4*)(x + (size_t)row * DIM))[tid];
  float s = v.x + v.y + v.z + v.w;
  float q = v.x * v.x + v.y * v.y + v.z * v.z + v.w * v.w;
  for (int off = 32; off; off >>= 1) {
    s += __shfl_down(s, off);
    q += __shfl_down(q, off);
  }
  __shared__ float sbuf[8];
  if (lane == 0) { sbuf[wave] = s; sbuf[4 + wave] = q; }
  __syncthreads();
  float tot = sbuf[0] + sbuf[1] + sbuf[2] + sbuf[3];
  float totq = sbuf[4] + sbuf[5] + sbuf[6] + sbuf[7];
  const float mean = tot * (1.0f / DIM);
  const float var = totq * (1.0f / DIM) - mean * mean;
  const float rs = rsqrtf(var + 1e-5f);
  const float4 wv = ((const float4*)w)[tid];
  const float4 bv = ((const float4*)b)[tid];
  ushort4 o;
  o.x = f2bf((v.x - mean) * rs * wv.x + bv.x);
  o.y = f2bf((v.y - mean) * rs * wv.y + bv.y);
  o.z = f2bf((v.z - mean) * rs * wv.z + bv.z);
  o.w = f2bf((v.w - mean) * rs * wv.w + bv.w);
  ((ushort4*)(h + (size_t)row * DIM))[tid] = o;
}

// ---------------- bf16 GEMM, B^T input, 128x128 tile, bf16 out ----------------
// C[m,n] = sum_k A[m,k]*Bt[n,k]; A: MxK, Bt: NxK. grid = (N/128, M/128), 256 thr.
__global__ __launch_bounds__(256) void gemm_bf16_kernel(const u16* __restrict__ A,
                                                        const u16* __restrict__ Bt,
                                                        u16* __restrict__ C,
                                                        int K, int N) {
  __shared__ u16 As[128 * 32];
  __shared__ u16 Bs[128 * 32];
  const int tid = threadIdx.x;
  const int lane = tid & 63, wave = tid >> 6;
  const int wm = wave >> 1, wn = wave & 1;
  const int row16 = lane & 15, quad = lane >> 4;
  const int bn = blockIdx.x, bm = blockIdx.y;
  f32x4 acc[4][4] = {};
  const u16* Ablk = A + (size_t)bm * 128 * K;
  const u16* Bblk = Bt + (size_t)bn * 128 * K;
  for (int k0 = 0; k0 < K; k0 += 32) {
#pragma unroll
    for (int i = 0; i < 2; ++i) {
      int c = tid + i * 256;
      int r = c >> 2, cc = (c & 3) * 8;
      async16(Ablk + (size_t)r * K + k0 + cc, &As[c * 8]);
      async16(Bblk + (size_t)r * K + k0 + cc, &Bs[c * 8]);
    }
    __syncthreads();
    short8 af[4], bfr[4];
#pragma unroll
    for (int i = 0; i < 4; ++i) {
      af[i] = *(const short8*)&As[(wm * 64 + i * 16 + row16) * 32 + quad * 8];
      bfr[i] = *(const short8*)&Bs[(wn * 64 + i * 16 + row16) * 32 + quad * 8];
    }
#pragma unroll
    for (int i = 0; i < 4; ++i)
#pragma unroll
      for (int j = 0; j < 4; ++j)
        acc[i][j] = __builtin_amdgcn_mfma_f32_16x16x32_bf16(af[i], bfr[j], acc[i][j], 0, 0, 0);
    __syncthreads();
  }
#pragma unroll
  for (int i = 0; i < 4; ++i) {
    int m = bm * 128 + wm * 64 + i * 16 + quad * 4;
#pragma unroll
    for (int j = 0; j < 4; ++j) {
      int n = bn * 128 + wn * 64 + j * 16 + row16;
#pragma unroll
      for (int r = 0; r < 4; ++r)
        C[(size_t)(m + r) * N + n] = f2bf(acc[i][j][r]);
    }
  }
}

// ---------------- out GEMM: fp32 out + residual ----------------
__global__ __launch_bounds__(256) void gemm_out_kernel(const u16* __restrict__ A,
                                                       const u16* __restrict__ Bt,
                                                       const float* __restrict__ resid,
                                                       float* __restrict__ C,
                                                       int K, int N) {
  __shared__ u16 As[128 * 32];
  __shared__ u16 Bs[128 * 32];
  const int tid = threadIdx.x;
  const int lane = tid & 63, wave = tid >> 6;
  const int wm = wave >> 1, wn = wave & 1;
  const int row16 = lane & 15, quad = lane >> 4;
  const int bn = blockIdx.x, bm = blockIdx.y;
  f32x4 acc[4][4] = {};
  const u16* Ablk = A + (size_t)bm * 128 * K;
  const u16* Bblk = Bt + (size_t)bn * 128 * K;
  for (int k0 = 0; k0 < K; k0 += 32) {
#pragma unroll
    for (int i = 0; i < 2; ++i) {
      int c = tid + i * 256;
      int r = c >> 2, cc = (c & 3) * 8;
      async16(Ablk + (size_t)r * K + k0 + cc, &As[c * 8]);
      async16(Bblk + (size_t)r * K + k0 + cc, &Bs[c * 8]);
    }
    __syncthreads();
    short8 af[4], bfr[4];
#pragma unroll
    for (int i = 0; i < 4; ++i) {
      af[i] = *(const short8*)&As[(wm * 64 + i * 16 + row16) * 32 + quad * 8];
      bfr[i] = *(const short8*)&Bs[(wn * 64 + i * 16 + row16) * 32 + quad * 8];
    }
#pragma unroll
    for (int i = 0; i < 4; ++i)
#pragma unroll
      for (int j = 0; j < 4; ++j)
        acc[i][j] = __builtin_amdgcn_mfma_f32_16x16x32_bf16(af[i], bfr[j], acc[i][j], 0, 0, 0);
    __syncthreads();
  }
#pragma unroll
  for (int i = 0; i < 4; ++i) {
    int m = bm * 128 + wm * 64 + i * 16 + quad * 4;
#pragma unroll
    for (int j = 0; j < 4; ++j) {
      int n = bn * 128 + wn * 64 + j * 16 + row16;
#pragma unroll
      for (int r = 0; r < 4; ++r) {
        size_t idx = (size_t)(m + r) * N + n;
        C[idx] = acc[i][j][r] + resid[idx];
      }
    }
  }
}

// ---------------- causal depthwise conv (k=4) + SiLU ----------------
__global__ void conv_silu_kernel(const u16* __restrict__ c1,
                                 const float* __restrict__ cw,
                                 u16* __restrict__ cs) {
  int idx = blockIdx.x * 256 + threadIdx.x;  // 8192*2048
  int d = idx & (DINNER - 1);
  int m = idx >> 11;
  int l = m & (SEQ - 1);
  float acc = 0.f;
#pragma unroll
  for (int k = 0; k < 4; ++k) {
    int ls = l + k - 3;
    if (ls >= 0) acc += bf2f(c1[(size_t)(m + k - 3) * DINNER + d]) * cw[d * 4 + k];
  }
  float s = acc / (1.f + __expf(-acc));
  cs[idx] = f2bf(s);
}

// ---------------- x_proj GEMM: M=8192, N=48(pad), K=2048 ----------------
__global__ __launch_bounds__(256) void gemm_w2_kernel(const u16* __restrict__ A,
                                                      const u16* __restrict__ Bt,
                                                      float* __restrict__ C) {
  __shared__ u16 As[128 * 32];
  __shared__ u16 Bs[48 * 32];
  const int tid = threadIdx.x;
  const int lane = tid & 63, wave = tid >> 6;
  const int row16 = lane & 15, quad = lane >> 4;
  const int bm = blockIdx.x;
  const int K = DINNER;
  f32x4 acc[2][3] = {};
  const u16* Ablk = A + (size_t)bm * 128 * K;
  for (int k0 = 0; k0 < K; k0 += 32) {
#pragma unroll
    for (int i = 0; i < 2; ++i) {
      int c = tid + i * 256;
      int r = c >> 2, cc = (c & 3) * 8;
      async16(Ablk + (size_t)r * K + k0 + cc, &As[c * 8]);
    }
    if (tid < 192) {
      int c = tid;
      int r = c >> 2, cc = (c & 3) * 8;
      async16(Bt + (size_t)r * K + k0 + cc, &Bs[c * 8]);
    }
    __syncthreads();
    short8 af[2], bfr[3];
#pragma unroll
    for (int i = 0; i < 2; ++i)
      af[i] = *(const short8*)&As[(wave * 32 + i * 16 + row16) * 32 + quad * 8];
#pragma unroll
    for (int j = 0; j < 3; ++j)
      bfr[j] = *(const short8*)&Bs[(j * 16 + row16) * 32 + quad * 8];
#pragma unroll
    for (int i = 0; i < 2; ++i)
#pragma unroll
      for (int j = 0; j < 3; ++j)
        acc[i][j] = __builtin_amdgcn_mfma_f32_16x16x32_bf16(af[i], bfr[j], acc[i][j], 0, 0, 0);
    __syncthreads();
  }
#pragma unroll
  for (int i = 0; i < 2; ++i) {
    int m = bm * 128 + wave * 32 + i * 16 + quad * 4;
#pragma unroll
    for (int j = 0; j < 3; ++j) {
      int n = j * 16 + row16;
#pragma unroll
      for (int r = 0; r < 4; ++r)
        C[(size_t)(m + r) * NPROJ_PAD + n] = acc[i][j][r];
    }
  }
}

// ---------------- selective scan ----------------
// grid 128: b = bid>>5, dchunk = bid&31 (64 channels each). 256 thr: 4/channel.
__global__ __launch_bounds__(256) void scan_kernel(const float* __restrict__ proj,
                                                   const u16* __restrict__ xs,
                                                   const float* __restrict__ dtw_,
                                                   const float* __restrict__ dtb_,
                                                   const float* __restrict__ A_log,
                                                   const float* __restrict__ Dp,
                                                   u16* __restrict__ ysil,
                                                   float* __restrict__ out_state) {
  __shared__ float P[64 * 36];   // per t: [0..15]=B, [16..31]=C, [32]=dt_in
  __shared__ u16 Xs[64 * 64];
  __shared__ u16 Ys[64 * 64];
  const int tid = threadIdx.x;
  const int sub = tid & 3, ch = tid >> 2;
  const int bid = blockIdx.x;
  const int b = bid >> 5, dchunk = bid & 31;
  const int d0 = dchunk * 64, d = d0 + ch;
  float An[4];
#pragma unroll
  for (int i = 0; i < 4; ++i) An[i] = -__expf(A_log[d * 16 + sub * 4 + i]);
  const float dtw = dtw_[d], dtb = dtb_[d], Dd = Dp[d];
  float st0 = 0.f, st1 = 0.f, st2 = 0.f, st3 = 0.f;
  const size_t mbase = (size_t)b * SEQ;

  for (int t0 = 0; t0 < SEQ; t0 += 64) {
    // stage proj rows (dt, B, C)
    if (tid < 64) {
      const float* pr = proj + (mbase + t0 + tid) * NPROJ_PAD;
      float* Pr = P + tid * 36;
#pragma unroll
      for (int j = 0; j < 32; ++j) Pr[j] = pr[1 + j];
      Pr[32] = pr[0];
    }
    // stage x (64 t x 64 ch bf16) as u32 pairs
    for (int i = tid; i < 2048; i += 256) {
      int tt = i >> 5, c2 = i & 31;
      ((u32*)Xs)[i] = ((const u32*)(xs + ((mbase + t0 + tt) << 11) + d0))[c2];
    }
    __syncthreads();
#pragma unroll 2
    for (int tt = 0; tt < 64; ++tt) {
      const float* Pr = P + tt * 36;
      const float4 Bv = *(const float4*)(Pr + sub * 4);
      const float4 Cv = *(const float4*)(Pr + 16 + sub * 4);
      const float dtin = Pr[32];
      float dt = fmaf(dtin, dtw, dtb);
      dt = (dt > 20.f) ? dt : log1pf(__expf(dt));
      const float xv = bf2f(Xs[tt * 64 + ch]);
      st0 = fmaf(__expf(An[0] * dt), st0, Bv.x * xv);
      st1 = fmaf(__expf(An[1] * dt), st1, Bv.y * xv);
      st2 = fmaf(__expf(An[2] * dt), st2, Bv.z * xv);
      st3 = fmaf(__expf(An[3] * dt), st3, Bv.w * xv);
      float part = st0 * Cv.x + st1 * Cv.y + st2 * Cv.z + st3 * Cv.w;
      part += __shfl_xor(part, 1);
      part += __shfl_xor(part, 2);
      const float y = fmaf(Dd, xv, part);
      const float sy = y / (1.f + __expf(-y));
      if (sub == 0) Ys[tt * 64 + ch] = f2bf(sy);
    }
    __syncthreads();
    // copy out silu(y); next stage writes P/Xs (disjoint), next compute guarded by barrier above
    for (int i = tid; i < 2048; i += 256) {
      int tt = i >> 5, c2 = i & 31;
      ((u32*)(ysil + ((mbase + t0 + tt) << 11) + d0))[c2] = ((const u32*)Ys)[i];
    }
  }
  // final state: (b, d, n) fp32
  float4 stv;
  stv.x = st0; stv.y = st1; stv.z = st2; stv.w = st3;
  *(float4*)(out_state + (mbase + d) * 16 + sub * 4) = stv;
}

// ---------------- launch ----------------
extern "C" void kernel_launch(void* const* d_in, const int* in_sizes, int n_in,
                              void* d_out, int out_size, void* d_ws, size_t ws_size,
                              hipStream_t stream) {
  const float* x = (const float*)d_in[0];
  const float* in_proj_w = (const float*)d_in[1];
  const float* conv_w = (const float*)d_in[2];
  const float* x_proj_w = (const float*)d_in[3];
  const float* dt_proj_w = (const float*)d_in[4];
  const float* dt_proj_b = (const float*)d_in[5];
  const float* A_log = (const float*)d_in[6];
  const float* Dvec = (const float*)d_in[7];
  const float* out_proj_w = (const float*)d_in[8];
  const float* norm_w = (const float*)d_in[9];
  const float* norm_b = (const float*)d_in[10];

  char* ws = (char*)d_ws;
  u16* h = (u16*)(ws + 0);                    // 8192x1024 bf16 (16 MB)
  u16* w1b = (u16*)(ws + 16777216);           // 2048x1024 bf16 (4 MB)
  u16* w3b = (u16*)(ws + 20971520);           // 1024x2048 bf16 (4 MB)
  u16* w2b = (u16*)(ws + 25165824);           // 48x2048 bf16 (0.19 MB)
  u16* c1 = (u16*)(ws + 25362432);            // 8192x2048 bf16 (32 MB)
  u16* ysil = c1;                             // aliased: c1 dead after conv
  u16* cs = (u16*)(ws + 58916864);            // 8192x2048 bf16 (32 MB)
  float* proj = (float*)(ws + 92471296);      // 8192x48 fp32 (1.5 MB)

  float* out = (float*)d_out;
  float* out_state = out + (size_t)4 * SEQ * DIM;

  cast_f2b_kernel<<<8192, 256, 0, stream>>>(in_proj_w, w1b, DINNER * DIM);
  cast_f2b_kernel<<<8192, 256, 0, stream>>>(out_proj_w, w3b, DIM * DINNER);
  cast_w2pad_kernel<<<384, 256, 0, stream>>>(x_proj_w, w2b);
  ln_kernel<<<8192, 256, 0, stream>>>(x, norm_w, norm_b, h);
  gemm_bf16_kernel<<<dim3(DINNER / 128, 64), 256, 0, stream>>>(h, w1b, c1, DIM, DINNER);
  conv_silu_kernel<<<65536, 256, 0, stream>>>(c1, conv_w, cs);
  gemm_w2_kernel<<<64, 256, 0, stream>>>(cs, w2b, proj);
  scan_kernel<<<128, 256, 0, stream>>>(proj, cs, dt_proj_w, dt_proj_b, A_log, Dvec, ysil,
                                       out_state);
  gemm_out_kernel<<<dim3(DIM / 128, 64), 256, 0, stream>>>(ysil, w3b, x, out, DINNER, DIM);
}

// Round 2
// 489.607 us; speedup vs baseline: 2.7022x; 2.7022x over previous
//
#include <hip/hip_runtime.h>

typedef unsigned short u16;
typedef unsigned int u32;
typedef __attribute__((ext_vector_type(8))) short short8;
typedef __attribute__((ext_vector_type(4))) float f32x4;

#define SEQ 2048
#define DIM 1024
#define DINNER 2048
#define NPROJ 33
#define NPROJ_PAD 48
#define LC 64   // chunk length
#define NC 32   // SEQ / LC

__device__ __forceinline__ u16 f2bf(float f) {
  union { float f; u32 u; } v; v.f = f;
  u32 r = (v.u + 0x7fffu + ((v.u >> 16) & 1u)) >> 16;
  return (u16)r;
}
__device__ __forceinline__ float bf2f(u16 s) {
  union { u32 u; float f; } v; v.u = ((u32)s) << 16;
  return v.f;
}
__device__ __forceinline__ float fexp2(float x) {
#if __has_builtin(__builtin_amdgcn_exp2f)
  return __builtin_amdgcn_exp2f(x);
#else
  return __expf(x * 0.69314718f);
#endif
}
// softplus, numerically stable, fast-math units
__device__ __forceinline__ float softplus(float x) {
  return fmaxf(x, 0.f) + __logf(1.f + __expf(-fabsf(x)));
}
__device__ __forceinline__ void async16(const void* g, void* l) {
  __builtin_amdgcn_global_load_lds(
      (const __attribute__((address_space(1))) u32*)g,
      (__attribute__((address_space(3))) u32*)l, 16, 0, 0);
}

// ---------------- cast kernels ----------------
__global__ void cast_f2b_kernel(const float* __restrict__ src, u16* __restrict__ dst, int n) {
  int i = blockIdx.x * 256 + threadIdx.x;
  if (i < n) dst[i] = f2bf(src[i]);
}

// x_proj_w (33,2048) -> padded bf16 (48,2048), rows 33..47 = 0
__global__ void cast_w2pad_kernel(const float* __restrict__ src, u16* __restrict__ dst) {
  int i = blockIdx.x * 256 + threadIdx.x;  // 48*2048
  int j = i >> 11, k = i & 2047;
  dst[i] = (j < NPROJ) ? f2bf(src[j * 2048 + k]) : (u16)0;
}

// ---------------- layernorm (row=1024) -> bf16 ----------------
__global__ __launch_bounds__(256) void ln_kernel(const float* __restrict__ x,
                                                 const float* __restrict__ w,
                                                 const float* __restrict__ b,
                                                 u16* __restrict__ h) {
  const int row = blockIdx.x;
  const int tid = threadIdx.x;
  const int lane = tid & 63, wave = tid >> 6;
  const float4 v = ((const float4*)(x + (size_t)row * DIM))[tid];
  float s = v.x + v.y + v.z + v.w;
  float q = v.x * v.x + v.y * v.y + v.z * v.z + v.w * v.w;
  for (int off = 32; off; off >>= 1) {
    s += __shfl_down(s, off);
    q += __shfl_down(q, off);
  }
  __shared__ float sbuf[8];
  if (lane == 0) { sbuf[wave] = s; sbuf[4 + wave] = q; }
  __syncthreads();
  float tot = sbuf[0] + sbuf[1] + sbuf[2] + sbuf[3];
  float totq = sbuf[4] + sbuf[5] + sbuf[6] + sbuf[7];
  const float mean = tot * (1.0f / DIM);
  const float var = totq * (1.0f / DIM) - mean * mean;
  const float rs = rsqrtf(var + 1e-5f);
  const float4 wv = ((const float4*)w)[tid];
  const float4 bv = ((const float4*)b)[tid];
  ushort4 o;
  o.x = f2bf((v.x - mean) * rs * wv.x + bv.x);
  o.y = f2bf((v.y - mean) * rs * wv.y + bv.y);
  o.z = f2bf((v.z - mean) * rs * wv.z + bv.z);
  o.w = f2bf((v.w - mean) * rs * wv.w + bv.w);
  ((ushort4*)(h + (size_t)row * DIM))[tid] = o;
}

// ---------------- bf16 GEMM, B^T input, 128x128 tile, bf16 out ----------------
__global__ __launch_bounds__(256) void gemm_bf16_kernel(const u16* __restrict__ A,
                                                        const u16* __restrict__ Bt,
                                                        u16* __restrict__ C,
                                                        int K, int N) {
  __shared__ u16 As[128 * 32];
  __shared__ u16 Bs[128 * 32];
  const int tid = threadIdx.x;
  const int lane = tid & 63, wave = tid >> 6;
  const int wm = wave >> 1, wn = wave & 1;
  const int row16 = lane & 15, quad = lane >> 4;
  const int bn = blockIdx.x, bm = blockIdx.y;
  f32x4 acc[4][4] = {};
  const u16* Ablk = A + (size_t)bm * 128 * K;
  const u16* Bblk = Bt + (size_t)bn * 128 * K;
  for (int k0 = 0; k0 < K; k0 += 32) {
#pragma unroll
    for (int i = 0; i < 2; ++i) {
      int c = tid + i * 256;
      int r = c >> 2, cc = (c & 3) * 8;
      async16(Ablk + (size_t)r * K + k0 + cc, &As[c * 8]);
      async16(Bblk + (size_t)r * K + k0 + cc, &Bs[c * 8]);
    }
    __syncthreads();
    short8 af[4], bfr[4];
#pragma unroll
    for (int i = 0; i < 4; ++i) {
      af[i] = *(const short8*)&As[(wm * 64 + i * 16 + row16) * 32 + quad * 8];
      bfr[i] = *(const short8*)&Bs[(wn * 64 + i * 16 + row16) * 32 + quad * 8];
    }
#pragma unroll
    for (int i = 0; i < 4; ++i)
#pragma unroll
      for (int j = 0; j < 4; ++j)
        acc[i][j] = __builtin_amdgcn_mfma_f32_16x16x32_bf16(af[i], bfr[j], acc[i][j], 0, 0, 0);
    __syncthreads();
  }
#pragma unroll
  for (int i = 0; i < 4; ++i) {
    int m = bm * 128 + wm * 64 + i * 16 + quad * 4;
#pragma unroll
    for (int j = 0; j < 4; ++j) {
      int n = bn * 128 + wn * 64 + j * 16 + row16;
#pragma unroll
      for (int r = 0; r < 4; ++r)
        C[(size_t)(m + r) * N + n] = f2bf(acc[i][j][r]);
    }
  }
}

// ---------------- out GEMM: fp32 out + residual ----------------
__global__ __launch_bounds__(256) void gemm_out_kernel(const u16* __restrict__ A,
                                                       const u16* __restrict__ Bt,
                                                       const float* __restrict__ resid,
                                                       float* __restrict__ C,
                                                       int K, int N) {
  __shared__ u16 As[128 * 32];
  __shared__ u16 Bs[128 * 32];
  const int tid = threadIdx.x;
  const int lane = tid & 63, wave = tid >> 6;
  const int wm = wave >> 1, wn = wave & 1;
  const int row16 = lane & 15, quad = lane >> 4;
  const int bn = blockIdx.x, bm = blockIdx.y;
  f32x4 acc[4][4] = {};
  const u16* Ablk = A + (size_t)bm * 128 * K;
  const u16* Bblk = Bt + (size_t)bn * 128 * K;
  for (int k0 = 0; k0 < K; k0 += 32) {
#pragma unroll
    for (int i = 0; i < 2; ++i) {
      int c = tid + i * 256;
      int r = c >> 2, cc = (c & 3) * 8;
      async16(Ablk + (size_t)r * K + k0 + cc, &As[c * 8]);
      async16(Bblk + (size_t)r * K + k0 + cc, &Bs[c * 8]);
    }
    __syncthreads();
    short8 af[4], bfr[4];
#pragma unroll
    for (int i = 0; i < 4; ++i) {
      af[i] = *(const short8*)&As[(wm * 64 + i * 16 + row16) * 32 + quad * 8];
      bfr[i] = *(const short8*)&Bs[(wn * 64 + i * 16 + row16) * 32 + quad * 8];
    }
#pragma unroll
    for (int i = 0; i < 4; ++i)
#pragma unroll
      for (int j = 0; j < 4; ++j)
        acc[i][j] = __builtin_amdgcn_mfma_f32_16x16x32_bf16(af[i], bfr[j], acc[i][j], 0, 0, 0);
    __syncthreads();
  }
#pragma unroll
  for (int i = 0; i < 4; ++i) {
    int m = bm * 128 + wm * 64 + i * 16 + quad * 4;
#pragma unroll
    for (int j = 0; j < 4; ++j) {
      int n = bn * 128 + wn * 64 + j * 16 + row16;
#pragma unroll
      for (int r = 0; r < 4; ++r) {
        size_t idx = (size_t)(m + r) * N + n;
        C[idx] = acc[i][j][r] + resid[idx];
      }
    }
  }
}

// ---------------- causal depthwise conv (k=4) + SiLU ----------------
__global__ void conv_silu_kernel(const u16* __restrict__ c1,
                                 const float* __restrict__ cw,
                                 u16* __restrict__ cs) {
  int idx = blockIdx.x * 256 + threadIdx.x;  // 8192*2048
  int d = idx & (DINNER - 1);
  int m = idx >> 11;
  int l = m & (SEQ - 1);
  float acc = 0.f;
#pragma unroll
  for (int k = 0; k < 4; ++k) {
    int ls = l + k - 3;
    if (ls >= 0) acc += bf2f(c1[(size_t)(m + k - 3) * DINNER + d]) * cw[d * 4 + k];
  }
  float s = acc / (1.f + __expf(-acc));
  cs[idx] = f2bf(s);
}

// ---------------- x_proj GEMM: M=8192, N=48(pad), K=2048 ----------------
__global__ __launch_bounds__(256) void gemm_w2_kernel(const u16* __restrict__ A,
                                                      const u16* __restrict__ Bt,
                                                      float* __restrict__ C) {
  __shared__ u16 As[128 * 32];
  __shared__ u16 Bs[48 * 32];
  const int tid = threadIdx.x;
  const int lane = tid & 63, wave = tid >> 6;
  const int row16 = lane & 15, quad = lane >> 4;
  const int bm = blockIdx.x;
  const int K = DINNER;
  f32x4 acc[2][3] = {};
  const u16* Ablk = A + (size_t)bm * 128 * K;
  for (int k0 = 0; k0 < K; k0 += 32) {
#pragma unroll
    for (int i = 0; i < 2; ++i) {
      int c = tid + i * 256;
      int r = c >> 2, cc = (c & 3) * 8;
      async16(Ablk + (size_t)r * K + k0 + cc, &As[c * 8]);
    }
    if (tid < 192) {
      int c = tid;
      int r = c >> 2, cc = (c & 3) * 8;
      async16(Bt + (size_t)r * K + k0 + cc, &Bs[c * 8]);
    }
    __syncthreads();
    short8 af[2], bfr[3];
#pragma unroll
    for (int i = 0; i < 2; ++i)
      af[i] = *(const short8*)&As[(wave * 32 + i * 16 + row16) * 32 + quad * 8];
#pragma unroll
    for (int j = 0; j < 3; ++j)
      bfr[j] = *(const short8*)&Bs[(j * 16 + row16) * 32 + quad * 8];
#pragma unroll
    for (int i = 0; i < 2; ++i)
#pragma unroll
      for (int j = 0; j < 3; ++j)
        acc[i][j] = __builtin_amdgcn_mfma_f32_16x16x32_bf16(af[i], bfr[j], acc[i][j], 0, 0, 0);
    __syncthreads();
  }
#pragma unroll
  for (int i = 0; i < 2; ++i) {
    int m = bm * 128 + wave * 32 + i * 16 + quad * 4;
#pragma unroll
    for (int j = 0; j < 3; ++j) {
      int n = j * 16 + row16;
#pragma unroll
      for (int r = 0; r < 4; ++r)
        C[(size_t)(m + r) * NPROJ_PAD + n] = acc[i][j][r];
    }
  }
}

// ======================= chunked selective scan =======================
// Layouts:
//   S buffer (ws): [b][c][d][n] fp32  (phase1 writes local chunk-final state;
//                                      phase2 rewrites it in place as chunk-INIT state)
//   Tdt   (ws): [b][c][d] fp32  (sum of dt over chunk)
// grid phase1/3: (DINNER/256, NC, B); 1 thread = 1 channel, 16 states in regs.

// ---- phase 1: local scan (init 0) -> S_loc, Tdt ----
__global__ __launch_bounds__(256) void scan_phase1(const float* __restrict__ proj,
                                                   const u16* __restrict__ xs,
                                                   const float* __restrict__ dtw_,
                                                   const float* __restrict__ dtb_,
                                                   const float* __restrict__ A_log,
                                                   float* __restrict__ S,
                                                   float* __restrict__ Tdt) {
  __shared__ float Bs[LC][16];
  __shared__ float DTin[LC];
  const int tid = threadIdx.x;
  const int d = blockIdx.x * 256 + tid;
  const int c = blockIdx.y;
  const int b = blockIdx.z;
  const size_t mrow = (size_t)b * SEQ + c * LC;
  for (int i = tid; i < LC * 16; i += 256) {
    int t = i >> 4, n = i & 15;
    Bs[t][n] = proj[(mrow + t) * NPROJ_PAD + 1 + n];
  }
  if (tid < LC) DTin[tid] = proj[(mrow + tid) * NPROJ_PAD];
  __syncthreads();
  float An2[16];
#pragma unroll
  for (int n = 0; n < 16; ++n) An2[n] = -__expf(A_log[d * 16 + n]) * 1.44269504f;
  const float dtw = dtw_[d], dtb = dtb_[d];
  float s[16];
#pragma unroll
  for (int n = 0; n < 16; ++n) s[n] = 0.f;
  float Tsum = 0.f;
  const u16* xp = xs + mrow * DINNER + d;
  u16 xnext = *xp;
#pragma unroll 2
  for (int t = 0; t < LC; ++t) {
    const float xv = bf2f(xnext);
    if (t + 1 < LC) xnext = xp[(size_t)(t + 1) * DINNER];
    const float sp = softplus(fmaf(DTin[t], dtw, dtb));
    Tsum += sp;
    const float4 B0 = *(const float4*)&Bs[t][0];
    const float4 B1 = *(const float4*)&Bs[t][4];
    const float4 B2 = *(const float4*)&Bs[t][8];
    const float4 B3 = *(const float4*)&Bs[t][12];
    const float bb[16] = {B0.x, B0.y, B0.z, B0.w, B1.x, B1.y, B1.z, B1.w,
                          B2.x, B2.y, B2.z, B2.w, B3.x, B3.y, B3.z, B3.w};
#pragma unroll
    for (int n = 0; n < 16; ++n)
      s[n] = fmaf(fexp2(An2[n] * sp), s[n], bb[n] * xv);
  }
  const size_t so = ((size_t)(b * NC + c) * DINNER + d) * 16;
#pragma unroll
  for (int n4 = 0; n4 < 4; ++n4)
    *(float4*)(S + so + n4 * 4) = make_float4(s[n4 * 4], s[n4 * 4 + 1], s[n4 * 4 + 2], s[n4 * 4 + 3]);
  Tdt[(size_t)(b * NC + c) * DINNER + d] = Tsum;
}

// ---- phase 2: cross-chunk combine; S becomes per-chunk INIT state ----
__global__ __launch_bounds__(256) void scan_phase2(const float* __restrict__ A_log,
                                                   float* __restrict__ S,
                                                   const float* __restrict__ Tdt,
                                                   float* __restrict__ out_state) {
  const int idx = blockIdx.x * 256 + threadIdx.x;  // 8192 = B*DINNER
  const int b = idx >> 11, d = idx & (DINNER - 1);
  float An2[16];
#pragma unroll
  for (int n = 0; n < 16; ++n) An2[n] = -__expf(A_log[d * 16 + n]) * 1.44269504f;
  float prev[16];
#pragma unroll
  for (int n = 0; n < 16; ++n) prev[n] = 0.f;
  for (int c = 0; c < NC; ++c) {
    const size_t so = ((size_t)(b * NC + c) * DINNER + d) * 16;
    const float T = Tdt[(size_t)(b * NC + c) * DINNER + d];
    float loc[16];
#pragma unroll
    for (int n4 = 0; n4 < 4; ++n4) {
      float4 v = *(const float4*)(S + so + n4 * 4);
      loc[n4 * 4] = v.x; loc[n4 * 4 + 1] = v.y; loc[n4 * 4 + 2] = v.z; loc[n4 * 4 + 3] = v.w;
    }
#pragma unroll
    for (int n4 = 0; n4 < 4; ++n4)
      *(float4*)(S + so + n4 * 4) =
          make_float4(prev[n4 * 4], prev[n4 * 4 + 1], prev[n4 * 4 + 2], prev[n4 * 4 + 3]);
#pragma unroll
    for (int n = 0; n < 16; ++n)
      prev[n] = fmaf(fexp2(An2[n] * T), prev[n], loc[n]);
  }
  // final state, layout [b][d][n] fp32
#pragma unroll
  for (int n4 = 0; n4 < 4; ++n4)
    *(float4*)(out_state + ((size_t)b * DINNER + d) * 16 + n4 * 4) =
        make_float4(prev[n4 * 4], prev[n4 * 4 + 1], prev[n4 * 4 + 2], prev[n4 * 4 + 3]);
}

// ---- phase 3: re-scan chunk from init state, emit silu(y) ----
__global__ __launch_bounds__(256) void scan_phase3(const float* __restrict__ proj,
                                                   const u16* __restrict__ xs,
                                                   const float* __restrict__ dtw_,
                                                   const float* __restrict__ dtb_,
                                                   const float* __restrict__ A_log,
                                                   const float* __restrict__ Dp,
                                                   const float* __restrict__ S,
                                                   u16* __restrict__ ysil) {
  __shared__ float Bs[LC][16];
  __shared__ float Cs[LC][16];
  __shared__ float DTin[LC];
  const int tid = threadIdx.x;
  const int d = blockIdx.x * 256 + tid;
  const int c = blockIdx.y;
  const int b = blockIdx.z;
  const size_t mrow = (size_t)b * SEQ + c * LC;
  for (int i = tid; i < LC * 16; i += 256) {
    int t = i >> 4, n = i & 15;
    Bs[t][n] = proj[(mrow + t) * NPROJ_PAD + 1 + n];
    Cs[t][n] = proj[(mrow + t) * NPROJ_PAD + 17 + n];
  }
  if (tid < LC) DTin[tid] = proj[(mrow + tid) * NPROJ_PAD];
  __syncthreads();
  float An2[16];
#pragma unroll
  for (int n = 0; n < 16; ++n) An2[n] = -__expf(A_log[d * 16 + n]) * 1.44269504f;
  const float dtw = dtw_[d], dtb = dtb_[d], Dd = Dp[d];
  float s[16];
  const size_t so = ((size_t)(b * NC + c) * DINNER + d) * 16;
#pragma unroll
  for (int n4 = 0; n4 < 4; ++n4) {
    float4 v = *(const float4*)(S + so + n4 * 4);
    s[n4 * 4] = v.x; s[n4 * 4 + 1] = v.y; s[n4 * 4 + 2] = v.z; s[n4 * 4 + 3] = v.w;
  }
  const u16* xp = xs + mrow * DINNER + d;
  u16* yp = ysil + mrow * DINNER + d;
  u16 xnext = *xp;
#pragma unroll 2
  for (int t = 0; t < LC; ++t) {
    const float xv = bf2f(xnext);
    if (t + 1 < LC) xnext = xp[(size_t)(t + 1) * DINNER];
    const float sp = softplus(fmaf(DTin[t], dtw, dtb));
    const float4 B0 = *(const float4*)&Bs[t][0];
    const float4 B1 = *(const float4*)&Bs[t][4];
    const float4 B2 = *(const float4*)&Bs[t][8];
    const float4 B3 = *(const float4*)&Bs[t][12];
    const float bb[16] = {B0.x, B0.y, B0.z, B0.w, B1.x, B1.y, B1.z, B1.w,
                          B2.x, B2.y, B2.z, B2.w, B3.x, B3.y, B3.z, B3.w};
#pragma unroll
    for (int n = 0; n < 16; ++n)
      s[n] = fmaf(fexp2(An2[n] * sp), s[n], bb[n] * xv);
    const float4 C0 = *(const float4*)&Cs[t][0];
    const float4 C1 = *(const float4*)&Cs[t][4];
    const float4 C2 = *(const float4*)&Cs[t][8];
    const float4 C3 = *(const float4*)&Cs[t][12];
    const float cc[16] = {C0.x, C0.y, C0.z, C0.w, C1.x, C1.y, C1.z, C1.w,
                          C2.x, C2.y, C2.z, C2.w, C3.x, C3.y, C3.z, C3.w};
    float y = Dd * xv;
#pragma unroll
    for (int n = 0; n < 16; ++n) y = fmaf(cc[n], s[n], y);
    const float sy = y / (1.f + __expf(-y));
    yp[(size_t)t * DINNER] = f2bf(sy);
  }
}

// ---------------- launch ----------------
extern "C" void kernel_launch(void* const* d_in, const int* in_sizes, int n_in,
                              void* d_out, int out_size, void* d_ws, size_t ws_size,
                              hipStream_t stream) {
  const float* x = (const float*)d_in[0];
  const float* in_proj_w = (const float*)d_in[1];
  const float* conv_w = (const float*)d_in[2];
  const float* x_proj_w = (const float*)d_in[3];
  const float* dt_proj_w = (const float*)d_in[4];
  const float* dt_proj_b = (const float*)d_in[5];
  const float* A_log = (const float*)d_in[6];
  const float* Dvec = (const float*)d_in[7];
  const float* out_proj_w = (const float*)d_in[8];
  const float* norm_w = (const float*)d_in[9];
  const float* norm_b = (const float*)d_in[10];

  char* ws = (char*)d_ws;
  u16* h = (u16*)(ws + 0);                    // 8192x1024 bf16 (16 MB)
  u16* w1b = (u16*)(ws + 16777216);           // 2048x1024 bf16 (4 MB)
  u16* w3b = (u16*)(ws + 20971520);           // 1024x2048 bf16 (4 MB)
  u16* w2b = (u16*)(ws + 25165824);           // 48x2048 bf16 (0.19 MB)
  u16* c1 = (u16*)(ws + 25362432);            // 8192x2048 bf16 (32 MB)
  u16* ysil = c1;                             // aliased: c1 dead after conv
  u16* cs = (u16*)(ws + 58916864);            // 8192x2048 bf16 (32 MB)
  float* proj = (float*)(ws + 92471296);      // 8192x48 fp32 (1.5 MB)
  float* Sbuf = (float*)(ws + 94044160);      // [b][c][d][n] fp32 (16 MB)
  float* Tdt = (float*)(ws + 110821376);      // [b][c][d] fp32 (1 MB)

  float* out = (float*)d_out;
  float* out_state = out + (size_t)4 * SEQ * DIM;

  cast_f2b_kernel<<<8192, 256, 0, stream>>>(in_proj_w, w1b, DINNER * DIM);
  cast_f2b_kernel<<<8192, 256, 0, stream>>>(out_proj_w, w3b, DIM * DINNER);
  cast_w2pad_kernel<<<384, 256, 0, stream>>>(x_proj_w, w2b);
  ln_kernel<<<8192, 256, 0, stream>>>(x, norm_w, norm_b, h);
  gemm_bf16_kernel<<<dim3(DINNER / 128, 64), 256, 0, stream>>>(h, w1b, c1, DIM, DINNER);
  conv_silu_kernel<<<65536, 256, 0, stream>>>(c1, conv_w, cs);
  gemm_w2_kernel<<<64, 256, 0, stream>>>(cs, w2b, proj);
  scan_phase1<<<dim3(DINNER / 256, NC, 4), 256, 0, stream>>>(proj, cs, dt_proj_w, dt_proj_b,
                                                             A_log, Sbuf, Tdt);
  scan_phase2<<<32, 256, 0, stream>>>(A_log, Sbuf, Tdt, out_state);
  scan_phase3<<<dim3(DINNER / 256, NC, 4), 256, 0, stream>>>(proj, cs, dt_proj_w, dt_proj_b,
                                                             A_log, Dvec, Sbuf, ysil);
  gemm_out_kernel<<<dim3(DIM / 128, 64), 256, 0, stream>>>(ysil, w3b, x, out, DINNER, DIM);
}

// Round 3
// 424.657 us; speedup vs baseline: 3.1155x; 1.1529x over previous
//
#include <hip/hip_runtime.h>

typedef unsigned short u16;
typedef unsigned int u32;
typedef __attribute__((ext_vector_type(8))) short short8;
typedef __attribute__((ext_vector_type(4))) float f32x4;
typedef __attribute__((ext_vector_type(8))) unsigned short ushort8_t;

#define SEQ 2048
#define DIM 1024
#define DINNER 2048
#define NPROJ 33
#define NPROJ_PAD 48
#define LC 64   // chunk length
#define NC 32   // SEQ / LC

__device__ __forceinline__ u16 f2bf(float f) {
  union { float f; u32 u; } v; v.f = f;
  u32 r = (v.u + 0x7fffu + ((v.u >> 16) & 1u)) >> 16;
  return (u16)r;
}
__device__ __forceinline__ float bf2f(u16 s) {
  union { u32 u; float f; } v; v.u = ((u32)s) << 16;
  return v.f;
}
__device__ __forceinline__ float fexp2(float x) {
#if __has_builtin(__builtin_amdgcn_exp2f)
  return __builtin_amdgcn_exp2f(x);
#else
  return __expf(x * 0.69314718f);
#endif
}
// softplus, numerically stable, fast-math units
__device__ __forceinline__ float softplus(float x) {
  return fmaxf(x, 0.f) + __logf(1.f + __expf(-fabsf(x)));
}
__device__ __forceinline__ void async16(const void* g, void* l) {
  __builtin_amdgcn_global_load_lds(
      (const __attribute__((address_space(1))) u32*)g,
      (__attribute__((address_space(3))) u32*)l, 16, 0, 0);
}

// ---------------- cast kernels (float4 -> ushort4) ----------------
__global__ void cast_f2b_kernel(const float* __restrict__ src, u16* __restrict__ dst, int n4) {
  int i = blockIdx.x * 256 + threadIdx.x;
  if (i < n4) {
    float4 v = ((const float4*)src)[i];
    ushort4 o;
    o.x = f2bf(v.x); o.y = f2bf(v.y); o.z = f2bf(v.z); o.w = f2bf(v.w);
    ((ushort4*)dst)[i] = o;
  }
}

// x_proj_w (33,2048) -> padded bf16 (48,2048), rows 33..47 = 0
__global__ void cast_w2pad_kernel(const float* __restrict__ src, u16* __restrict__ dst) {
  int i = blockIdx.x * 256 + threadIdx.x;  // 48*2048
  int j = i >> 11, k = i & 2047;
  dst[i] = (j < NPROJ) ? f2bf(src[j * 2048 + k]) : (u16)0;
}

// ---------------- layernorm (row=1024) -> bf16 ----------------
__global__ __launch_bounds__(256) void ln_kernel(const float* __restrict__ x,
                                                 const float* __restrict__ w,
                                                 const float* __restrict__ b,
                                                 u16* __restrict__ h) {
  const int row = blockIdx.x;
  const int tid = threadIdx.x;
  const int lane = tid & 63, wave = tid >> 6;
  const float4 v = ((const float4*)(x + (size_t)row * DIM))[tid];
  float s = v.x + v.y + v.z + v.w;
  float q = v.x * v.x + v.y * v.y + v.z * v.z + v.w * v.w;
  for (int off = 32; off; off >>= 1) {
    s += __shfl_down(s, off);
    q += __shfl_down(q, off);
  }
  __shared__ float sbuf[8];
  if (lane == 0) { sbuf[wave] = s; sbuf[4 + wave] = q; }
  __syncthreads();
  float tot = sbuf[0] + sbuf[1] + sbuf[2] + sbuf[3];
  float totq = sbuf[4] + sbuf[5] + sbuf[6] + sbuf[7];
  const float mean = tot * (1.0f / DIM);
  const float var = totq * (1.0f / DIM) - mean * mean;
  const float rs = rsqrtf(var + 1e-5f);
  const float4 wv = ((const float4*)w)[tid];
  const float4 bv = ((const float4*)b)[tid];
  ushort4 o;
  o.x = f2bf((v.x - mean) * rs * wv.x + bv.x);
  o.y = f2bf((v.y - mean) * rs * wv.y + bv.y);
  o.z = f2bf((v.z - mean) * rs * wv.z + bv.z);
  o.w = f2bf((v.w - mean) * rs * wv.w + bv.w);
  ((ushort4*)(h + (size_t)row * DIM))[tid] = o;
}

// ---------------- bf16 GEMM, B^T input, 128x128 tile, bf16 out ----------------
__global__ __launch_bounds__(256) void gemm_bf16_kernel(const u16* __restrict__ A,
                                                        const u16* __restrict__ Bt,
                                                        u16* __restrict__ C,
                                                        int K, int N) {
  __shared__ u16 As[128 * 32];
  __shared__ u16 Bs[128 * 32];
  const int tid = threadIdx.x;
  const int lane = tid & 63, wave = tid >> 6;
  const int wm = wave >> 1, wn = wave & 1;
  const int row16 = lane & 15, quad = lane >> 4;
  const int bn = blockIdx.x, bm = blockIdx.y;
  f32x4 acc[4][4] = {};
  const u16* Ablk = A + (size_t)bm * 128 * K;
  const u16* Bblk = Bt + (size_t)bn * 128 * K;
  for (int k0 = 0; k0 < K; k0 += 32) {
#pragma unroll
    for (int i = 0; i < 2; ++i) {
      int c = tid + i * 256;
      int r = c >> 2, cc = (c & 3) * 8;
      async16(Ablk + (size_t)r * K + k0 + cc, &As[c * 8]);
      async16(Bblk + (size_t)r * K + k0 + cc, &Bs[c * 8]);
    }
    __syncthreads();
    short8 af[4], bfr[4];
#pragma unroll
    for (int i = 0; i < 4; ++i) {
      af[i] = *(const short8*)&As[(wm * 64 + i * 16 + row16) * 32 + quad * 8];
      bfr[i] = *(const short8*)&Bs[(wn * 64 + i * 16 + row16) * 32 + quad * 8];
    }
#pragma unroll
    for (int i = 0; i < 4; ++i)
#pragma unroll
      for (int j = 0; j < 4; ++j)
        acc[i][j] = __builtin_amdgcn_mfma_f32_16x16x32_bf16(af[i], bfr[j], acc[i][j], 0, 0, 0);
    __syncthreads();
  }
#pragma unroll
  for (int i = 0; i < 4; ++i) {
    int m = bm * 128 + wm * 64 + i * 16 + quad * 4;
#pragma unroll
    for (int j = 0; j < 4; ++j) {
      int n = bn * 128 + wn * 64 + j * 16 + row16;
#pragma unroll
      for (int r = 0; r < 4; ++r)
        C[(size_t)(m + r) * N + n] = f2bf(acc[i][j][r]);
    }
  }
}

// ---------------- out GEMM: fp32 out + residual ----------------
__global__ __launch_bounds__(256) void gemm_out_kernel(const u16* __restrict__ A,
                                                       const u16* __restrict__ Bt,
                                                       const float* __restrict__ resid,
                                                       float* __restrict__ C,
                                                       int K, int N) {
  __shared__ u16 As[128 * 32];
  __shared__ u16 Bs[128 * 32];
  const int tid = threadIdx.x;
  const int lane = tid & 63, wave = tid >> 6;
  const int wm = wave >> 1, wn = wave & 1;
  const int row16 = lane & 15, quad = lane >> 4;
  const int bn = blockIdx.x, bm = blockIdx.y;
  f32x4 acc[4][4] = {};
  const u16* Ablk = A + (size_t)bm * 128 * K;
  const u16* Bblk = Bt + (size_t)bn * 128 * K;
  for (int k0 = 0; k0 < K; k0 += 32) {
#pragma unroll
    for (int i = 0; i < 2; ++i) {
      int c = tid + i * 256;
      int r = c >> 2, cc = (c & 3) * 8;
      async16(Ablk + (size_t)r * K + k0 + cc, &As[c * 8]);
      async16(Bblk + (size_t)r * K + k0 + cc, &Bs[c * 8]);
    }
    __syncthreads();
    short8 af[4], bfr[4];
#pragma unroll
    for (int i = 0; i < 4; ++i) {
      af[i] = *(const short8*)&As[(wm * 64 + i * 16 + row16) * 32 + quad * 8];
      bfr[i] = *(const short8*)&Bs[(wn * 64 + i * 16 + row16) * 32 + quad * 8];
    }
#pragma unroll
    for (int i = 0; i < 4; ++i)
#pragma unroll
      for (int j = 0; j < 4; ++j)
        acc[i][j] = __builtin_amdgcn_mfma_f32_16x16x32_bf16(af[i], bfr[j], acc[i][j], 0, 0, 0);
    __syncthreads();
  }
#pragma unroll
  for (int i = 0; i < 4; ++i) {
    int m = bm * 128 + wm * 64 + i * 16 + quad * 4;
#pragma unroll
    for (int j = 0; j < 4; ++j) {
      int n = bn * 128 + wn * 64 + j * 16 + row16;
#pragma unroll
      for (int r = 0; r < 4; ++r) {
        size_t idx = (size_t)(m + r) * N + n;
        C[idx] = acc[i][j][r] + resid[idx];
      }
    }
  }
}

// ---------------- causal depthwise conv (k=4) + SiLU, vectorized ----------------
// 1 block = 8 consecutive time rows; 1 thread = 8 channels; rolling 4-row window.
// Loads/stores are 16B/lane. grid = B*SEQ/8 = 1024.
__global__ __launch_bounds__(256) void conv_silu_kernel(const u16* __restrict__ c1,
                                                        const float* __restrict__ cw,
                                                        u16* __restrict__ cs) {
  const int tid = threadIdx.x;
  const int dg = tid * 8;
  const size_t m0 = (size_t)blockIdx.x * 8;
  const int l0 = (int)(m0 & (SEQ - 1));
  float w[4][8];
  {
    const float4* cw4 = (const float4*)(cw + (size_t)dg * 4);
#pragma unroll
    for (int c = 0; c < 8; ++c) {
      float4 v = cw4[c];
      w[0][c] = v.x; w[1][c] = v.y; w[2][c] = v.z; w[3][c] = v.w;
    }
  }
  const u16* base = c1 + m0 * DINNER + dg;
  ushort8_t win0, win1, win2, win3;
  const ushort8_t zero = (ushort8_t)0;
  if (l0 == 0) {
    win0 = zero; win1 = zero; win2 = zero;
  } else {
    win0 = *(const ushort8_t*)(base - 3 * DINNER);
    win1 = *(const ushort8_t*)(base - 2 * DINNER);
    win2 = *(const ushort8_t*)(base - 1 * DINNER);
  }
  win3 = *(const ushort8_t*)(base);
#pragma unroll
  for (int t = 0; t < 8; ++t) {
    ushort8_t nxt = win3;
    if (t < 7) nxt = *(const ushort8_t*)(base + (size_t)(t + 1) * DINNER);
    ushort8_t o;
#pragma unroll
    for (int c = 0; c < 8; ++c) {
      float acc = bf2f((u16)win0[c]) * w[0][c];
      acc = fmaf(bf2f((u16)win1[c]), w[1][c], acc);
      acc = fmaf(bf2f((u16)win2[c]), w[2][c], acc);
      acc = fmaf(bf2f((u16)win3[c]), w[3][c], acc);
      const float s = acc / (1.f + __expf(-acc));
      o[c] = (unsigned short)f2bf(s);
    }
    *(ushort8_t*)(cs + (m0 + t) * DINNER + dg) = o;
    win0 = win1; win1 = win2; win2 = win3; win3 = nxt;
  }
}

// ---------------- x_proj GEMM: M=8192, N=48(pad), K=2048 ----------------
__global__ __launch_bounds__(256) void gemm_w2_kernel(const u16* __restrict__ A,
                                                      const u16* __restrict__ Bt,
                                                      float* __restrict__ C) {
  __shared__ u16 As[128 * 32];
  __shared__ u16 Bs[48 * 32];
  const int tid = threadIdx.x;
  const int lane = tid & 63, wave = tid >> 6;
  const int row16 = lane & 15, quad = lane >> 4;
  const int bm = blockIdx.x;
  const int K = DINNER;
  f32x4 acc[2][3] = {};
  const u16* Ablk = A + (size_t)bm * 128 * K;
  for (int k0 = 0; k0 < K; k0 += 32) {
#pragma unroll
    for (int i = 0; i < 2; ++i) {
      int c = tid + i * 256;
      int r = c >> 2, cc = (c & 3) * 8;
      async16(Ablk + (size_t)r * K + k0 + cc, &As[c * 8]);
    }
    if (tid < 192) {
      int c = tid;
      int r = c >> 2, cc = (c & 3) * 8;
      async16(Bt + (size_t)r * K + k0 + cc, &Bs[c * 8]);
    }
    __syncthreads();
    short8 af[2], bfr[3];
#pragma unroll
    for (int i = 0; i < 2; ++i)
      af[i] = *(const short8*)&As[(wave * 32 + i * 16 + row16) * 32 + quad * 8];
#pragma unroll
    for (int j = 0; j < 3; ++j)
      bfr[j] = *(const short8*)&Bs[(j * 16 + row16) * 32 + quad * 8];
#pragma unroll
    for (int i = 0; i < 2; ++i)
#pragma unroll
      for (int j = 0; j < 3; ++j)
        acc[i][j] = __builtin_amdgcn_mfma_f32_16x16x32_bf16(af[i], bfr[j], acc[i][j], 0, 0, 0);
    __syncthreads();
  }
#pragma unroll
  for (int i = 0; i < 2; ++i) {
    int m = bm * 128 + wave * 32 + i * 16 + quad * 4;
#pragma unroll
    for (int j = 0; j < 3; ++j) {
      int n = j * 16 + row16;
#pragma unroll
      for (int r = 0; r < 4; ++r)
        C[(size_t)(m + r) * NPROJ_PAD + n] = acc[i][j][r];
    }
  }
}

// ======================= chunked selective scan =======================
// ---- phase 1: local scan (init 0) -> S_loc, Tdt ----
__global__ __launch_bounds__(256) void scan_phase1(const float* __restrict__ proj,
                                                   const u16* __restrict__ xs,
                                                   const float* __restrict__ dtw_,
                                                   const float* __restrict__ dtb_,
                                                   const float* __restrict__ A_log,
                                                   float* __restrict__ S,
                                                   float* __restrict__ Tdt) {
  __shared__ float Bs[LC][16];
  __shared__ float DTin[LC];
  const int tid = threadIdx.x;
  const int d = blockIdx.x * 256 + tid;
  const int c = blockIdx.y;
  const int b = blockIdx.z;
  const size_t mrow = (size_t)b * SEQ + c * LC;
  for (int i = tid; i < LC * 16; i += 256) {
    int t = i >> 4, n = i & 15;
    Bs[t][n] = proj[(mrow + t) * NPROJ_PAD + 1 + n];
  }
  if (tid < LC) DTin[tid] = proj[(mrow + tid) * NPROJ_PAD];
  __syncthreads();
  float An2[16];
#pragma unroll
  for (int n = 0; n < 16; ++n) An2[n] = -__expf(A_log[d * 16 + n]) * 1.44269504f;
  const float dtw = dtw_[d], dtb = dtb_[d];
  float s[16];
#pragma unroll
  for (int n = 0; n < 16; ++n) s[n] = 0.f;
  float Tsum = 0.f;
  const u16* xp = xs + mrow * DINNER + d;
  u16 xnext = *xp;
#pragma unroll 2
  for (int t = 0; t < LC; ++t) {
    const float xv = bf2f(xnext);
    if (t + 1 < LC) xnext = xp[(size_t)(t + 1) * DINNER];
    const float sp = softplus(fmaf(DTin[t], dtw, dtb));
    Tsum += sp;
    const float4 B0 = *(const float4*)&Bs[t][0];
    const float4 B1 = *(const float4*)&Bs[t][4];
    const float4 B2 = *(const float4*)&Bs[t][8];
    const float4 B3 = *(const float4*)&Bs[t][12];
    const float bb[16] = {B0.x, B0.y, B0.z, B0.w, B1.x, B1.y, B1.z, B1.w,
                          B2.x, B2.y, B2.z, B2.w, B3.x, B3.y, B3.z, B3.w};
#pragma unroll
    for (int n = 0; n < 16; ++n)
      s[n] = fmaf(fexp2(An2[n] * sp), s[n], bb[n] * xv);
  }
  const size_t so = ((size_t)(b * NC + c) * DINNER + d) * 16;
#pragma unroll
  for (int n4 = 0; n4 < 4; ++n4)
    *(float4*)(S + so + n4 * 4) = make_float4(s[n4 * 4], s[n4 * 4 + 1], s[n4 * 4 + 2], s[n4 * 4 + 3]);
  Tdt[(size_t)(b * NC + c) * DINNER + d] = Tsum;
}

// ---- phase 2: cross-chunk combine; S becomes per-chunk INIT state ----
__global__ __launch_bounds__(256) void scan_phase2(const float* __restrict__ A_log,
                                                   float* __restrict__ S,
                                                   const float* __restrict__ Tdt,
                                                   float* __restrict__ out_state) {
  const int idx = blockIdx.x * 256 + threadIdx.x;  // 8192 = B*DINNER
  const int b = idx >> 11, d = idx & (DINNER - 1);
  float An2[16];
#pragma unroll
  for (int n = 0; n < 16; ++n) An2[n] = -__expf(A_log[d * 16 + n]) * 1.44269504f;
  float prev[16];
#pragma unroll
  for (int n = 0; n < 16; ++n) prev[n] = 0.f;
  for (int c = 0; c < NC; ++c) {
    const size_t so = ((size_t)(b * NC + c) * DINNER + d) * 16;
    const float T = Tdt[(size_t)(b * NC + c) * DINNER + d];
    float loc[16];
#pragma unroll
    for (int n4 = 0; n4 < 4; ++n4) {
      float4 v = *(const float4*)(S + so + n4 * 4);
      loc[n4 * 4] = v.x; loc[n4 * 4 + 1] = v.y; loc[n4 * 4 + 2] = v.z; loc[n4 * 4 + 3] = v.w;
    }
#pragma unroll
    for (int n4 = 0; n4 < 4; ++n4)
      *(float4*)(S + so + n4 * 4) =
          make_float4(prev[n4 * 4], prev[n4 * 4 + 1], prev[n4 * 4 + 2], prev[n4 * 4 + 3]);
#pragma unroll
    for (int n = 0; n < 16; ++n)
      prev[n] = fmaf(fexp2(An2[n] * T), prev[n], loc[n]);
  }
  // final state, layout [b][d][n] fp32
#pragma unroll
  for (int n4 = 0; n4 < 4; ++n4)
    *(float4*)(out_state + ((size_t)b * DINNER + d) * 16 + n4 * 4) =
        make_float4(prev[n4 * 4], prev[n4 * 4 + 1], prev[n4 * 4 + 2], prev[n4 * 4 + 3]);
}

// ---- phase 3: re-scan chunk from init state, emit silu(y) ----
__global__ __launch_bounds__(256) void scan_phase3(const float* __restrict__ proj,
                                                   const u16* __restrict__ xs,
                                                   const float* __restrict__ dtw_,
                                                   const float* __restrict__ dtb_,
                                                   const float* __restrict__ A_log,
                                                   const float* __restrict__ Dp,
                                                   const float* __restrict__ S,
                                                   u16* __restrict__ ysil) {
  __shared__ float Bs[LC][16];
  __shared__ float Cs[LC][16];
  __shared__ float DTin[LC];
  const int tid = threadIdx.x;
  const int d = blockIdx.x * 256 + tid;
  const int c = blockIdx.y;
  const int b = blockIdx.z;
  const size_t mrow = (size_t)b * SEQ + c * LC;
  for (int i = tid; i < LC * 16; i += 256) {
    int t = i >> 4, n = i & 15;
    Bs[t][n] = proj[(mrow + t) * NPROJ_PAD + 1 + n];
    Cs[t][n] = proj[(mrow + t) * NPROJ_PAD + 17 + n];
  }
  if (tid < LC) DTin[tid] = proj[(mrow + tid) * NPROJ_PAD];
  __syncthreads();
  float An2[16];
#pragma unroll
  for (int n = 0; n < 16; ++n) An2[n] = -__expf(A_log[d * 16 + n]) * 1.44269504f;
  const float dtw = dtw_[d], dtb = dtb_[d], Dd = Dp[d];
  float s[16];
  const size_t so = ((size_t)(b * NC + c) * DINNER + d) * 16;
#pragma unroll
  for (int n4 = 0; n4 < 4; ++n4) {
    float4 v = *(const float4*)(S + so + n4 * 4);
    s[n4 * 4] = v.x; s[n4 * 4 + 1] = v.y; s[n4 * 4 + 2] = v.z; s[n4 * 4 + 3] = v.w;
  }
  const u16* xp = xs + mrow * DINNER + d;
  u16* yp = ysil + mrow * DINNER + d;
  u16 xnext = *xp;
#pragma unroll 2
  for (int t = 0; t < LC; ++t) {
    const float xv = bf2f(xnext);
    if (t + 1 < LC) xnext = xp[(size_t)(t + 1) * DINNER];
    const float sp = softplus(fmaf(DTin[t], dtw, dtb));
    const float4 B0 = *(const float4*)&Bs[t][0];
    const float4 B1 = *(const float4*)&Bs[t][4];
    const float4 B2 = *(const float4*)&Bs[t][8];
    const float4 B3 = *(const float4*)&Bs[t][12];
    const float bb[16] = {B0.x, B0.y, B0.z, B0.w, B1.x, B1.y, B1.z, B1.w,
                          B2.x, B2.y, B2.z, B2.w, B3.x, B3.y, B3.z, B3.w};
#pragma unroll
    for (int n = 0; n < 16; ++n)
      s[n] = fmaf(fexp2(An2[n] * sp), s[n], bb[n] * xv);
    const float4 C0 = *(const float4*)&Cs[t][0];
    const float4 C1 = *(const float4*)&Cs[t][4];
    const float4 C2 = *(const float4*)&Cs[t][8];
    const float4 C3 = *(const float4*)&Cs[t][12];
    const float cc[16] = {C0.x, C0.y, C0.z, C0.w, C1.x, C1.y, C1.z, C1.w,
                          C2.x, C2.y, C2.z, C2.w, C3.x, C3.y, C3.z, C3.w};
    float y = Dd * xv;
#pragma unroll
    for (int n = 0; n < 16; ++n) y = fmaf(cc[n], s[n], y);
    const float sy = y / (1.f + __expf(-y));
    yp[(size_t)t * DINNER] = f2bf(sy);
  }
}

// ---------------- launch ----------------
extern "C" void kernel_launch(void* const* d_in, const int* in_sizes, int n_in,
                              void* d_out, int out_size, void* d_ws, size_t ws_size,
                              hipStream_t stream) {
  const float* x = (const float*)d_in[0];
  const float* in_proj_w = (const float*)d_in[1];
  const float* conv_w = (const float*)d_in[2];
  const float* x_proj_w = (const float*)d_in[3];
  const float* dt_proj_w = (const float*)d_in[4];
  const float* dt_proj_b = (const float*)d_in[5];
  const float* A_log = (const float*)d_in[6];
  const float* Dvec = (const float*)d_in[7];
  const float* out_proj_w = (const float*)d_in[8];
  const float* norm_w = (const float*)d_in[9];
  const float* norm_b = (const float*)d_in[10];

  char* ws = (char*)d_ws;
  u16* h = (u16*)(ws + 0);                    // 8192x1024 bf16 (16 MB)
  u16* w1b = (u16*)(ws + 16777216);           // 2048x1024 bf16 (4 MB)
  u16* w3b = (u16*)(ws + 20971520);           // 1024x2048 bf16 (4 MB)
  u16* w2b = (u16*)(ws + 25165824);           // 48x2048 bf16 (0.19 MB)
  u16* c1 = (u16*)(ws + 25362432);            // 8192x2048 bf16 (32 MB)
  u16* ysil = c1;                             // aliased: c1 dead after conv
  u16* cs = (u16*)(ws + 58916864);            // 8192x2048 bf16 (32 MB)
  float* proj = (float*)(ws + 92471296);      // 8192x48 fp32 (1.5 MB)
  float* Sbuf = (float*)(ws + 94044160);      // [b][c][d][n] fp32 (16 MB)
  float* Tdt = (float*)(ws + 110821376);      // [b][c][d] fp32 (1 MB)

  float* out = (float*)d_out;
  float* out_state = out + (size_t)4 * SEQ * DIM;

  cast_f2b_kernel<<<2048, 256, 0, stream>>>(in_proj_w, w1b, DINNER * DIM / 4);
  cast_f2b_kernel<<<2048, 256, 0, stream>>>(out_proj_w, w3b, DIM * DINNER / 4);
  cast_w2pad_kernel<<<384, 256, 0, stream>>>(x_proj_w, w2b);
  ln_kernel<<<8192, 256, 0, stream>>>(x, norm_w, norm_b, h);
  gemm_bf16_kernel<<<dim3(DINNER / 128, 64), 256, 0, stream>>>(h, w1b, c1, DIM, DINNER);
  conv_silu_kernel<<<1024, 256, 0, stream>>>(c1, conv_w, cs);
  gemm_w2_kernel<<<64, 256, 0, stream>>>(cs, w2b, proj);
  scan_phase1<<<dim3(DINNER / 256, NC, 4), 256, 0, stream>>>(proj, cs, dt_proj_w, dt_proj_b,
                                                             A_log, Sbuf, Tdt);
  scan_phase2<<<32, 256, 0, stream>>>(A_log, Sbuf, Tdt, out_state);
  scan_phase3<<<dim3(DINNER / 256, NC, 4), 256, 0, stream>>>(proj, cs, dt_proj_w, dt_proj_b,
                                                             A_log, Dvec, Sbuf, ysil);
  gemm_out_kernel<<<dim3(DIM / 128, 64), 256, 0, stream>>>(ysil, w3b, x, out, DINNER, DIM);
}